// Round 9
// baseline (191.498 us; speedup 1.0000x reference)
//
#include <hip/hip_runtime.h>
#include <hip/hip_bf16.h>
#include <math.h>

// Problem constants (fixed shapes from the reference)
constexpr int B_  = 4;
constexpr int N_  = 10000;
constexpr int E_  = 160000;
constexpr int D_  = 128;
constexpr int H_  = 4;
constexpr int O_  = 64;
constexpr float NEG_SLOPE = 0.2f;

using short8 = __attribute__((ext_vector_type(8))) short;
using f32x4  = __attribute__((ext_vector_type(4))) float;

static __device__ __forceinline__ unsigned short f2bf(float f) {
    unsigned u = __float_as_uint(f);
    u += 0x7fffu + ((u >> 16) & 1u);           // RN-even
    return (unsigned short)(u >> 16);
}
static __device__ __forceinline__ float bf2f(unsigned short h) {
    return __uint_as_float((unsigned)h << 16);
}

// ---------------------------------------------------------------------------
// k_prep, 128 blocks:
//   block d: W1t/W2t bf16 split of Wsrc[d][h][o] -> [c][d], c = o*4+h;
//            v_src[d][h], v_dst[d][h] row reductions.
//   all blocks: grid-stride zero of deg[]; block 0: c[h].
// ---------------------------------------------------------------------------
__global__ __launch_bounds__(256) void k_prep(
    const float* __restrict__ Wsrc, const float* __restrict__ att_src,
    const float* __restrict__ att_dst,
    const float* __restrict__ W_edge, const float* __restrict__ att_edge,
    unsigned short* __restrict__ W1t, unsigned short* __restrict__ W2t,
    float* __restrict__ vsrc, float* __restrict__ vdst,
    int* __restrict__ deg, float* __restrict__ c)
{
    const int d = blockIdx.x;
    const int t = threadIdx.x;
    const int h = t >> 6;

    for (int i = d * 256 + t; i < N_; i += 128 * 256) deg[i] = 0;

    const float wv = Wsrc[(size_t)d * 256 + t];
    const unsigned short w1 = f2bf(wv);
    const unsigned short w2 = f2bf(wv - bf2f(w1));
    const int cc = ((t & 63) << 2) | h;      // o*4 + head
    W1t[(size_t)cc * 128 + d] = w1;
    W2t[(size_t)cc * 128 + d] = w2;

    float vs = wv * att_src[t];
    float vd = wv * att_dst[t];
#pragma unroll
    for (int off = 32; off > 0; off >>= 1) {
        vs += __shfl_down(vs, off, 64);
        vd += __shfl_down(vd, off, 64);
    }
    if ((t & 63) == 0) {
        vsrc[d * 4 + h] = vs;
        vdst[d * 4 + h] = vd;
    }

    if (d == 0) {
        float v = W_edge[t] * att_edge[t];
#pragma unroll
        for (int off = 32; off > 0; off >>= 1) v += __shfl_down(v, off, 64);
        if ((t & 63) == 0) c[h] = v;
    }
}

// ---------------------------------------------------------------------------
// k_gemm (MFMA) + fused dst-histogram.
// rows = flat b*N+n (40000), cols c = o*4+head (256), K = 128.
// 32 rows/block (1250 blocks). Each block also histograms 128 edges
// (1250*128 = E; deg was zeroed by k_prep which precedes us in-stream).
// Split-precision bf16: h = x1@W1 + x1@W2 + x2@W1 (fp32-accurate).
// ---------------------------------------------------------------------------
__global__ __launch_bounds__(256) void k_gemm(
    const float* __restrict__ x, const int* __restrict__ ei,
    const unsigned short* __restrict__ W1t, const unsigned short* __restrict__ W2t,
    const float* __restrict__ vsrc, const float* __restrict__ vdst,
    unsigned short* __restrict__ hbw, float* __restrict__ asrc, float* __restrict__ adst,
    int* __restrict__ deg)
{
    constexpr int ROWS = 32;
    constexpr int APAD = 136;                // ushort stride (128+8)
    __shared__ unsigned short A1[ROWS * APAD];
    __shared__ unsigned short A2[ROWS * APAD];
    __shared__ float4 vsL[128];
    __shared__ float4 vdL[128];

    const int t = threadIdx.x;
    const int w = t >> 6;
    const int lane = t & 63;
    const int i = lane & 15;
    const int q = lane >> 4;
    const size_t rowbase = (size_t)blockIdx.x * ROWS;

    // fused histogram: 128 edges per block (atomics into L2-resident deg)
    if (t < 128) {
        const int ee = blockIdx.x * 128 + t;
        atomicAdd(&deg[ei[E_ + ee]], 1);
    }

    {
        const float4* xg = (const float4*)(x + rowbase * D_);
#pragma unroll
        for (int it = 0; it < 4; ++it) {
            const int idx = it * 256 + t;
            const int row = idx >> 5;
            const int c4  = idx & 31;
            float4 xv = xg[idx];
            ushort4 h1, h2;
            h1.x = f2bf(xv.x); h2.x = f2bf(xv.x - bf2f(h1.x));
            h1.y = f2bf(xv.y); h2.y = f2bf(xv.y - bf2f(h1.y));
            h1.z = f2bf(xv.z); h2.z = f2bf(xv.z - bf2f(h1.z));
            h1.w = f2bf(xv.w); h2.w = f2bf(xv.w - bf2f(h1.w));
            *(ushort4*)&A1[row * APAD + c4 * 4] = h1;
            *(ushort4*)&A2[row * APAD + c4 * 4] = h2;
        }
        if (t < 128) vsL[t] = ((const float4*)vsrc)[t];
        else         vdL[t - 128] = ((const float4*)vdst)[t - 128];
    }
    __syncthreads();

    f32x4 acc[2][4];
#pragma unroll
    for (int tl = 0; tl < 2; ++tl)
#pragma unroll
        for (int ctl = 0; ctl < 4; ++ctl) acc[tl][ctl] = (f32x4){0.f, 0.f, 0.f, 0.f};

#pragma unroll
    for (int ks = 0; ks < 4; ++ks) {
        const int a0off = i * APAD + ks * 32 + q * 8;
        const int a1off = (16 + i) * APAD + ks * 32 + q * 8;
        short8 a1t0 = *(const short8*)&A1[a0off];
        short8 a2t0 = *(const short8*)&A2[a0off];
        short8 a1t1 = *(const short8*)&A1[a1off];
        short8 a2t1 = *(const short8*)&A2[a1off];

        short8 b1[4], b2[4];
#pragma unroll
        for (int ctl = 0; ctl < 4; ++ctl) {
            const size_t boff = (size_t)((w * 4 + ctl) * 16 + i) * 128 + ks * 32 + q * 8;
            b1[ctl] = *(const short8*)&W1t[boff];
            b2[ctl] = *(const short8*)&W2t[boff];
        }
#pragma unroll
        for (int ctl = 0; ctl < 4; ++ctl) {
            acc[0][ctl] = __builtin_amdgcn_mfma_f32_16x16x32_bf16(a1t0, b1[ctl], acc[0][ctl], 0, 0, 0);
            acc[0][ctl] = __builtin_amdgcn_mfma_f32_16x16x32_bf16(a2t0, b1[ctl], acc[0][ctl], 0, 0, 0);
            acc[0][ctl] = __builtin_amdgcn_mfma_f32_16x16x32_bf16(a1t0, b2[ctl], acc[0][ctl], 0, 0, 0);
            acc[1][ctl] = __builtin_amdgcn_mfma_f32_16x16x32_bf16(a1t1, b1[ctl], acc[1][ctl], 0, 0, 0);
            acc[1][ctl] = __builtin_amdgcn_mfma_f32_16x16x32_bf16(a2t1, b1[ctl], acc[1][ctl], 0, 0, 0);
            acc[1][ctl] = __builtin_amdgcn_mfma_f32_16x16x32_bf16(a1t1, b2[ctl], acc[1][ctl], 0, 0, 0);
        }
    }

    {   // exact a_src/a_dst from (A1+A2) . v
        const int r = lane >> 3, g = lane & 7;
        const int row_l = w * 8 + r;
        float s0 = 0, s1 = 0, s2 = 0, s3 = 0, d0 = 0, d1 = 0, d2 = 0, d3 = 0;
#pragma unroll
        for (int dd4 = 0; dd4 < 4; ++dd4) {
            const int db = g * 16 + dd4 * 4;
            ushort4 u1 = *(const ushort4*)&A1[row_l * APAD + db];
            ushort4 u2 = *(const ushort4*)&A2[row_l * APAD + db];
            const float xv0 = bf2f(u1.x) + bf2f(u2.x);
            const float xv1 = bf2f(u1.y) + bf2f(u2.y);
            const float xv2 = bf2f(u1.z) + bf2f(u2.z);
            const float xv3 = bf2f(u1.w) + bf2f(u2.w);
            float4 vsa = vsL[db + 0], vda = vdL[db + 0];
            float4 vsb = vsL[db + 1], vdb = vdL[db + 1];
            float4 vsc = vsL[db + 2], vdc = vdL[db + 2];
            float4 vsd = vsL[db + 3], vdd = vdL[db + 3];
            s0 = fmaf(xv0, vsa.x, s0); s1 = fmaf(xv0, vsa.y, s1);
            s2 = fmaf(xv0, vsa.z, s2); s3 = fmaf(xv0, vsa.w, s3);
            d0 = fmaf(xv0, vda.x, d0); d1 = fmaf(xv0, vda.y, d1);
            d2 = fmaf(xv0, vda.z, d2); d3 = fmaf(xv0, vda.w, d3);
            s0 = fmaf(xv1, vsb.x, s0); s1 = fmaf(xv1, vsb.y, s1);
            s2 = fmaf(xv1, vsb.z, s2); s3 = fmaf(xv1, vsb.w, s3);
            d0 = fmaf(xv1, vdb.x, d0); d1 = fmaf(xv1, vdb.y, d1);
            d2 = fmaf(xv1, vdb.z, d2); d3 = fmaf(xv1, vdb.w, d3);
            s0 = fmaf(xv2, vsc.x, s0); s1 = fmaf(xv2, vsc.y, s1);
            s2 = fmaf(xv2, vsc.z, s2); s3 = fmaf(xv2, vsc.w, s3);
            d0 = fmaf(xv2, vdc.x, d0); d1 = fmaf(xv2, vdc.y, d1);
            d2 = fmaf(xv2, vdc.z, d2); d3 = fmaf(xv2, vdc.w, d3);
            s0 = fmaf(xv3, vsd.x, s0); s1 = fmaf(xv3, vsd.y, s1);
            s2 = fmaf(xv3, vsd.z, s2); s3 = fmaf(xv3, vsd.w, s3);
            d0 = fmaf(xv3, vdd.x, d0); d1 = fmaf(xv3, vdd.y, d1);
            d2 = fmaf(xv3, vdd.z, d2); d3 = fmaf(xv3, vdd.w, d3);
        }
#pragma unroll
        for (int off = 4; off > 0; off >>= 1) {
            s0 += __shfl_down(s0, off, 64); s1 += __shfl_down(s1, off, 64);
            s2 += __shfl_down(s2, off, 64); s3 += __shfl_down(s3, off, 64);
            d0 += __shfl_down(d0, off, 64); d1 += __shfl_down(d1, off, 64);
            d2 += __shfl_down(d2, off, 64); d3 += __shfl_down(d3, off, 64);
        }
        if (g == 0) {
            const size_t rg = rowbase + row_l;
            *(float4*)&asrc[rg * 4] = make_float4(s0, s1, s2, s3);
            *(float4*)&adst[rg * 4] = make_float4(d0, d1, d2, d3);
        }
    }

#pragma unroll
    for (int tl = 0; tl < 2; ++tl) {
#pragma unroll
        for (int ctl = 0; ctl < 4; ++ctl) {
#pragma unroll
            for (int r = 0; r < 4; ++r) {
                const size_t rg = rowbase + tl * 16 + q * 4 + r;
                hbw[rg * 256 + (w * 4 + ctl) * 16 + i] = f2bf(acc[tl][ctl][r]);
            }
        }
    }
}

// ---------------------------------------------------------------------------
// k_scan: single-block exclusive prefix sum, 2 barriers total.
// Thread t owns nodes t*10 .. t*10+9 (1000 active threads).
// ---------------------------------------------------------------------------
__global__ __launch_bounds__(1024) void k_scan(const int* __restrict__ deg,
                                               int* __restrict__ rowptr,
                                               int* __restrict__ cursor)
{
    __shared__ int wsum[16], wexcl[16];
    const int t = threadIdx.x, wv = t >> 6, ln = t & 63;
    const int base = t * 10;
    int v[10];
    int tot = 0;
    if (base < N_) {
#pragma unroll
        for (int i = 0; i < 10; ++i) { v[i] = deg[base + i]; tot += v[i]; }
    }
    int incl = tot;
#pragma unroll
    for (int off = 1; off < 64; off <<= 1) {
        int u = __shfl_up(incl, off, 64);
        if (ln >= off) incl += u;
    }
    if (ln == 63) wsum[wv] = incl;
    __syncthreads();
    if (wv == 0 && ln < 16) {
        int s = wsum[ln];
        int si = s;
#pragma unroll
        for (int off = 1; off < 16; off <<= 1) {
            int u = __shfl_up(si, off, 64);
            if (ln >= off) si += u;
        }
        wexcl[ln] = si - s;
    }
    __syncthreads();
    if (base < N_) {
        int run = wexcl[wv] + incl - tot;
#pragma unroll
        for (int i = 0; i < 10; ++i) {
            rowptr[base + i] = run; cursor[base + i] = run; run += v[i];
        }
    }
    if (t == 0) rowptr[N_] = E_;
}

// ---------------------------------------------------------------------------
// k_place: counting-sort edges by dst; payload packed as int2{src, ea_bits}
// ---------------------------------------------------------------------------
__global__ __launch_bounds__(256) void k_place(
    const int* __restrict__ ei, const float* __restrict__ eattr,
    int* __restrict__ cursor, int2* __restrict__ srcea)
{
    const int e = blockIdx.x * 256 + threadIdx.x;
    if (e >= E_) return;
    const int dst = ei[E_ + e];
    const int pos = atomicAdd(&cursor[dst], 1);
    srcea[pos] = make_int2(ei[e], __float_as_int(eattr[e]));
}

// ---------------------------------------------------------------------------
// k_agg: one wave per dst, ALL 4 batches.
//   Chunk phase: lane = (edge j = lane>>2, batch b = lane&3) -> 16 edges x
//   4 batches = full 64-lane utilization (mean deg 16 => 1 chunk). srcea read
//   once (not 4x). p4 + src -> LDS; per-lane denominator partials.
//   Inner loop: lane = o; per edge 4 INDEPENDENT hb-row gathers (one per
//   batch, 4-deep MLP) + 5 uniform LDS broadcasts; acc[b][h] in registers.
//   Denominator: xor-butterfly over j-lanes once at the end. Non-atomic out.
// ---------------------------------------------------------------------------
__global__ __launch_bounds__(256) void k_agg(
    const int* __restrict__ rowptr, const int2* __restrict__ srcea,
    const float* __restrict__ asrc, const float* __restrict__ adst,
    const float* __restrict__ cvec, const unsigned short* __restrict__ hbu,
    const float* __restrict__ bias, float* __restrict__ out)
{
    __shared__ float pS[4][16][4][4];    // [wave][j][b][h]  4 KB
    __shared__ int   srcS[4][16];        // [wave][j]
    __shared__ float qS[4][4][4];        // [wave][b][h]

    const int wave = threadIdx.x >> 6;
    const int lane = threadIdx.x & 63;
    const int dst  = blockIdx.x * 4 + wave;

    const int start = rowptr[dst];
    const int end   = rowptr[dst + 1];

    const int jj = lane >> 2;            // edge slot 0..15
    const int jb = lane & 3;             // batch (chunk phase)

    const float4 cc = *(const float4*)cvec;
    const float4 ad = *(const float4*)&adst[((size_t)jb * N_ + dst) * 4];

    float acc[4][4];
#pragma unroll
    for (int b = 0; b < 4; ++b)
#pragma unroll
        for (int h = 0; h < 4; ++h) acc[b][h] = 0.f;
    float qp0 = 0.f, qp1 = 0.f, qp2 = 0.f, qp3 = 0.f;

    for (int c0 = start; c0 < end; c0 += 16) {
        const int jl = c0 + jj;
        const bool valid = jl < end;
        const int2 rec = srcea[valid ? jl : start];
        const int   src = rec.x;
        const float ea  = __int_as_float(rec.y);
        const float4 as = *(const float4*)&asrc[((size_t)jb * N_ + src) * 4];
        float4 al;
        al.x = as.x + ad.x + ea * cc.x;
        al.y = as.y + ad.y + ea * cc.y;
        al.z = as.z + ad.z + ea * cc.z;
        al.w = as.w + ad.w + ea * cc.w;
        al.x = al.x > 0.f ? al.x : NEG_SLOPE * al.x;
        al.y = al.y > 0.f ? al.y : NEG_SLOPE * al.y;
        al.z = al.z > 0.f ? al.z : NEG_SLOPE * al.z;
        al.w = al.w > 0.f ? al.w : NEG_SLOPE * al.w;
        const float px = valid ? __expf(al.x) : 0.f;
        const float py = valid ? __expf(al.y) : 0.f;
        const float pz = valid ? __expf(al.z) : 0.f;
        const float pw = valid ? __expf(al.w) : 0.f;
        qp0 += px; qp1 += py; qp2 += pz; qp3 += pw;

        *(float4*)&pS[wave][jj][jb][0] = make_float4(px, py, pz, pw);
        if (jb == 0) srcS[wave][jj] = src;
        __builtin_amdgcn_wave_barrier();

        const int cnt = min(16, end - c0);
        for (int j = 0; j < cnt; ++j) {
            const int sj = srcS[wave][j];                        // uniform
            const float4 p0 = *(const float4*)&pS[wave][j][0][0];
            const float4 p1 = *(const float4*)&pS[wave][j][1][0];
            const float4 p2 = *(const float4*)&pS[wave][j][2][0];
            const float4 p3 = *(const float4*)&pS[wave][j][3][0];
            const size_t rb = (size_t)sj * 256 + lane * 4;
            const ushort4 h0 = *(const ushort4*)&hbu[rb];
            const ushort4 h1 = *(const ushort4*)&hbu[rb + (size_t)N_ * 256];
            const ushort4 h2 = *(const ushort4*)&hbu[rb + (size_t)2 * N_ * 256];
            const ushort4 h3 = *(const ushort4*)&hbu[rb + (size_t)3 * N_ * 256];
            acc[0][0] = fmaf(p0.x, bf2f(h0.x), acc[0][0]);
            acc[0][1] = fmaf(p0.y, bf2f(h0.y), acc[0][1]);
            acc[0][2] = fmaf(p0.z, bf2f(h0.z), acc[0][2]);
            acc[0][3] = fmaf(p0.w, bf2f(h0.w), acc[0][3]);
            acc[1][0] = fmaf(p1.x, bf2f(h1.x), acc[1][0]);
            acc[1][1] = fmaf(p1.y, bf2f(h1.y), acc[1][1]);
            acc[1][2] = fmaf(p1.z, bf2f(h1.z), acc[1][2]);
            acc[1][3] = fmaf(p1.w, bf2f(h1.w), acc[1][3]);
            acc[2][0] = fmaf(p2.x, bf2f(h2.x), acc[2][0]);
            acc[2][1] = fmaf(p2.y, bf2f(h2.y), acc[2][1]);
            acc[2][2] = fmaf(p2.z, bf2f(h2.z), acc[2][2]);
            acc[2][3] = fmaf(p2.w, bf2f(h2.w), acc[2][3]);
            acc[3][0] = fmaf(p3.x, bf2f(h3.x), acc[3][0]);
            acc[3][1] = fmaf(p3.y, bf2f(h3.y), acc[3][1]);
            acc[3][2] = fmaf(p3.z, bf2f(h3.z), acc[3][2]);
            acc[3][3] = fmaf(p3.w, bf2f(h3.w), acc[3][3]);
        }
        __builtin_amdgcn_wave_barrier();
    }

    // denominator: reduce over the 16 j-lanes (stride-4 xor butterfly)
#pragma unroll
    for (int off = 4; off <= 32; off <<= 1) {
        qp0 += __shfl_xor(qp0, off, 64);
        qp1 += __shfl_xor(qp1, off, 64);
        qp2 += __shfl_xor(qp2, off, 64);
        qp3 += __shfl_xor(qp3, off, 64);
    }
    if (jj == 0) *(float4*)&qS[wave][jb][0] = make_float4(qp0, qp1, qp2, qp3);
    __builtin_amdgcn_wave_barrier();

    const float bs = bias[lane];
#pragma unroll
    for (int b = 0; b < 4; ++b) {
        const float4 q = *(const float4*)&qS[wave][b][0];
        const float r = acc[b][0] / fmaxf(q.x, 1e-16f)
                      + acc[b][1] / fmaxf(q.y, 1e-16f)
                      + acc[b][2] / fmaxf(q.z, 1e-16f)
                      + acc[b][3] / fmaxf(q.w, 1e-16f);
        out[((size_t)b * N_ + dst) * O_ + lane] = 0.25f * r + bs;
    }
}

// ---------------------------------------------------------------------------
extern "C" void kernel_launch(void* const* d_in, const int* in_sizes, int n_in,
                              void* d_out, int out_size, void* d_ws, size_t ws_size,
                              hipStream_t stream)
{
    (void)in_sizes; (void)n_in; (void)out_size; (void)ws_size;
    const float* x        = (const float*)d_in[0];
    const int*   ei       = (const int*)d_in[1];     // int64 in ref -> int32 here
    const float* eattr    = (const float*)d_in[2];
    const float* Wsrc     = (const float*)d_in[3];
    const float* att_src  = (const float*)d_in[4];
    const float* att_dst  = (const float*)d_in[5];
    const float* W_edge   = (const float*)d_in[6];
    const float* att_edge = (const float*)d_in[7];
    const float* bias     = (const float*)d_in[8];
    float* out = (float*)d_out;

    // workspace carve-up (16B-aligned chunks)
    char* w = (char*)d_ws;
    auto take = [&](size_t bytes) { char* p = w; w += (bytes + 15) & ~size_t(15); return p; };
    unsigned short* hb   = (unsigned short*)take((size_t)B_ * N_ * O_ * H_ * 2); // 20.48 MB
    float* asrc    = (float*)take((size_t)B_ * N_ * H_ * 4);                     // 640 KB
    float* adst    = (float*)take((size_t)B_ * N_ * H_ * 4);
    float* c       = (float*)take(4 * 4);
    unsigned short* W1t = (unsigned short*)take((size_t)256 * 128 * 2);          // 64 KB
    unsigned short* W2t = (unsigned short*)take((size_t)256 * 128 * 2);
    float* vsrc    = (float*)take((size_t)128 * 4 * 4);                          // 2 KB
    float* vdst    = (float*)take((size_t)128 * 4 * 4);
    int* deg       = (int*)take((size_t)N_ * 4);
    int* rowptr    = (int*)take((size_t)(N_ + 1) * 4);
    int* cursor    = (int*)take((size_t)N_ * 4);
    int2* srcea    = (int2*)take((size_t)E_ * 8);                                // 1.28 MB

    hipLaunchKernelGGL(k_prep, dim3(128), dim3(256), 0, stream,
                       Wsrc, att_src, att_dst, W_edge, att_edge,
                       W1t, W2t, vsrc, vdst, deg, c);
    hipLaunchKernelGGL(k_gemm, dim3((B_ * N_) / 32), dim3(256), 0, stream,
                       x, ei, W1t, W2t, vsrc, vdst, hb, asrc, adst, deg);
    hipLaunchKernelGGL(k_scan, dim3(1), dim3(1024), 0, stream, deg, rowptr, cursor);
    hipLaunchKernelGGL(k_place, dim3((E_ + 255) / 256), dim3(256), 0, stream,
                       ei, eattr, cursor, srcea);
    hipLaunchKernelGGL(k_agg, dim3(N_ / 4), dim3(256), 0, stream,
                       rowptr, srcea, asrc, adst, c, hb, bias, out);
}

// Round 10
// 169.373 us; speedup vs baseline: 1.1306x; 1.1306x over previous
//
#include <hip/hip_runtime.h>
#include <hip/hip_bf16.h>
#include <math.h>

// Problem constants (fixed shapes from the reference)
constexpr int B_  = 4;
constexpr int N_  = 10000;
constexpr int E_  = 160000;
constexpr int D_  = 128;
constexpr int H_  = 4;
constexpr int O_  = 64;
constexpr float NEG_SLOPE = 0.2f;

using short8 = __attribute__((ext_vector_type(8))) short;
using f32x4  = __attribute__((ext_vector_type(4))) float;

static __device__ __forceinline__ unsigned short f2bf(float f) {
    unsigned u = __float_as_uint(f);
    u += 0x7fffu + ((u >> 16) & 1u);           // RN-even
    return (unsigned short)(u >> 16);
}
static __device__ __forceinline__ float bf2f(unsigned short h) {
    return __uint_as_float((unsigned)h << 16);
}

// ---------------------------------------------------------------------------
// k_prep, 128 blocks:
//   block d: W1t/W2t bf16 split of Wsrc[d][h][o] -> [c][d], c = o*4+h;
//            v_src[d][h], v_dst[d][h] row reductions.
//   all blocks: grid-stride zero of deg[]; block 0: c[h].
// ---------------------------------------------------------------------------
__global__ __launch_bounds__(256) void k_prep(
    const float* __restrict__ Wsrc, const float* __restrict__ att_src,
    const float* __restrict__ att_dst,
    const float* __restrict__ W_edge, const float* __restrict__ att_edge,
    unsigned short* __restrict__ W1t, unsigned short* __restrict__ W2t,
    float* __restrict__ vsrc, float* __restrict__ vdst,
    int* __restrict__ deg, float* __restrict__ c)
{
    const int d = blockIdx.x;
    const int t = threadIdx.x;
    const int h = t >> 6;

    for (int i = d * 256 + t; i < N_; i += 128 * 256) deg[i] = 0;

    const float wv = Wsrc[(size_t)d * 256 + t];
    const unsigned short w1 = f2bf(wv);
    const unsigned short w2 = f2bf(wv - bf2f(w1));
    const int cc = ((t & 63) << 2) | h;      // o*4 + head
    W1t[(size_t)cc * 128 + d] = w1;
    W2t[(size_t)cc * 128 + d] = w2;

    float vs = wv * att_src[t];
    float vd = wv * att_dst[t];
#pragma unroll
    for (int off = 32; off > 0; off >>= 1) {
        vs += __shfl_down(vs, off, 64);
        vd += __shfl_down(vd, off, 64);
    }
    if ((t & 63) == 0) {
        vsrc[d * 4 + h] = vs;
        vdst[d * 4 + h] = vd;
    }

    if (d == 0) {
        float v = W_edge[t] * att_edge[t];
#pragma unroll
        for (int off = 32; off > 0; off >>= 1) v += __shfl_down(v, off, 64);
        if ((t & 63) == 0) c[h] = v;
    }
}

// ---------------------------------------------------------------------------
// k_gemm (MFMA) + fused dst-histogram WITH per-edge rank capture.
// rows = flat b*N+n (40000), cols c = o*4+head (256), K = 128.
// 32 rows/block (1250 blocks); each block histograms 128 edges and records
// rank[e] so k_place needs no atomics.
// Split-precision bf16: h = x1@W1 + x1@W2 + x2@W1 (fp32-accurate).
// ---------------------------------------------------------------------------
__global__ __launch_bounds__(256) void k_gemm(
    const float* __restrict__ x, const int* __restrict__ ei,
    const unsigned short* __restrict__ W1t, const unsigned short* __restrict__ W2t,
    const float* __restrict__ vsrc, const float* __restrict__ vdst,
    unsigned short* __restrict__ hbw, float* __restrict__ asrc, float* __restrict__ adst,
    int* __restrict__ deg, int* __restrict__ rank)
{
    constexpr int ROWS = 32;
    constexpr int APAD = 136;                // ushort stride (128+8)
    __shared__ unsigned short A1[ROWS * APAD];
    __shared__ unsigned short A2[ROWS * APAD];
    __shared__ float4 vsL[128];
    __shared__ float4 vdL[128];

    const int t = threadIdx.x;
    const int w = t >> 6;
    const int lane = t & 63;
    const int i = lane & 15;
    const int q = lane >> 4;
    const size_t rowbase = (size_t)blockIdx.x * ROWS;

    // fused histogram + rank: 128 edges per block
    if (t < 128) {
        const int ee = blockIdx.x * 128 + t;
        rank[ee] = atomicAdd(&deg[ei[E_ + ee]], 1);
    }

    {
        const float4* xg = (const float4*)(x + rowbase * D_);
#pragma unroll
        for (int it = 0; it < 4; ++it) {
            const int idx = it * 256 + t;
            const int row = idx >> 5;
            const int c4  = idx & 31;
            float4 xv = xg[idx];
            ushort4 h1, h2;
            h1.x = f2bf(xv.x); h2.x = f2bf(xv.x - bf2f(h1.x));
            h1.y = f2bf(xv.y); h2.y = f2bf(xv.y - bf2f(h1.y));
            h1.z = f2bf(xv.z); h2.z = f2bf(xv.z - bf2f(h1.z));
            h1.w = f2bf(xv.w); h2.w = f2bf(xv.w - bf2f(h1.w));
            *(ushort4*)&A1[row * APAD + c4 * 4] = h1;
            *(ushort4*)&A2[row * APAD + c4 * 4] = h2;
        }
        if (t < 128) vsL[t] = ((const float4*)vsrc)[t];
        else         vdL[t - 128] = ((const float4*)vdst)[t - 128];
    }
    __syncthreads();

    f32x4 acc[2][4];
#pragma unroll
    for (int tl = 0; tl < 2; ++tl)
#pragma unroll
        for (int ctl = 0; ctl < 4; ++ctl) acc[tl][ctl] = (f32x4){0.f, 0.f, 0.f, 0.f};

#pragma unroll
    for (int ks = 0; ks < 4; ++ks) {
        const int a0off = i * APAD + ks * 32 + q * 8;
        const int a1off = (16 + i) * APAD + ks * 32 + q * 8;
        short8 a1t0 = *(const short8*)&A1[a0off];
        short8 a2t0 = *(const short8*)&A2[a0off];
        short8 a1t1 = *(const short8*)&A1[a1off];
        short8 a2t1 = *(const short8*)&A2[a1off];

        short8 b1[4], b2[4];
#pragma unroll
        for (int ctl = 0; ctl < 4; ++ctl) {
            const size_t boff = (size_t)((w * 4 + ctl) * 16 + i) * 128 + ks * 32 + q * 8;
            b1[ctl] = *(const short8*)&W1t[boff];
            b2[ctl] = *(const short8*)&W2t[boff];
        }
#pragma unroll
        for (int ctl = 0; ctl < 4; ++ctl) {
            acc[0][ctl] = __builtin_amdgcn_mfma_f32_16x16x32_bf16(a1t0, b1[ctl], acc[0][ctl], 0, 0, 0);
            acc[0][ctl] = __builtin_amdgcn_mfma_f32_16x16x32_bf16(a2t0, b1[ctl], acc[0][ctl], 0, 0, 0);
            acc[0][ctl] = __builtin_amdgcn_mfma_f32_16x16x32_bf16(a1t0, b2[ctl], acc[0][ctl], 0, 0, 0);
            acc[1][ctl] = __builtin_amdgcn_mfma_f32_16x16x32_bf16(a1t1, b1[ctl], acc[1][ctl], 0, 0, 0);
            acc[1][ctl] = __builtin_amdgcn_mfma_f32_16x16x32_bf16(a2t1, b1[ctl], acc[1][ctl], 0, 0, 0);
            acc[1][ctl] = __builtin_amdgcn_mfma_f32_16x16x32_bf16(a1t1, b2[ctl], acc[1][ctl], 0, 0, 0);
        }
    }

    {   // exact a_src/a_dst from (A1+A2) . v
        const int r = lane >> 3, g = lane & 7;
        const int row_l = w * 8 + r;
        float s0 = 0, s1 = 0, s2 = 0, s3 = 0, d0 = 0, d1 = 0, d2 = 0, d3 = 0;
#pragma unroll
        for (int dd4 = 0; dd4 < 4; ++dd4) {
            const int db = g * 16 + dd4 * 4;
            ushort4 u1 = *(const ushort4*)&A1[row_l * APAD + db];
            ushort4 u2 = *(const ushort4*)&A2[row_l * APAD + db];
            const float xv0 = bf2f(u1.x) + bf2f(u2.x);
            const float xv1 = bf2f(u1.y) + bf2f(u2.y);
            const float xv2 = bf2f(u1.z) + bf2f(u2.z);
            const float xv3 = bf2f(u1.w) + bf2f(u2.w);
            float4 vsa = vsL[db + 0], vda = vdL[db + 0];
            float4 vsb = vsL[db + 1], vdb = vdL[db + 1];
            float4 vsc = vsL[db + 2], vdc = vdL[db + 2];
            float4 vsd = vsL[db + 3], vdd = vdL[db + 3];
            s0 = fmaf(xv0, vsa.x, s0); s1 = fmaf(xv0, vsa.y, s1);
            s2 = fmaf(xv0, vsa.z, s2); s3 = fmaf(xv0, vsa.w, s3);
            d0 = fmaf(xv0, vda.x, d0); d1 = fmaf(xv0, vda.y, d1);
            d2 = fmaf(xv0, vda.z, d2); d3 = fmaf(xv0, vda.w, d3);
            s0 = fmaf(xv1, vsb.x, s0); s1 = fmaf(xv1, vsb.y, s1);
            s2 = fmaf(xv1, vsb.z, s2); s3 = fmaf(xv1, vsb.w, s3);
            d0 = fmaf(xv1, vdb.x, d0); d1 = fmaf(xv1, vdb.y, d1);
            d2 = fmaf(xv1, vdb.z, d2); d3 = fmaf(xv1, vdb.w, d3);
            s0 = fmaf(xv2, vsc.x, s0); s1 = fmaf(xv2, vsc.y, s1);
            s2 = fmaf(xv2, vsc.z, s2); s3 = fmaf(xv2, vsc.w, s3);
            d0 = fmaf(xv2, vdc.x, d0); d1 = fmaf(xv2, vdc.y, d1);
            d2 = fmaf(xv2, vdc.z, d2); d3 = fmaf(xv2, vdc.w, d3);
            s0 = fmaf(xv3, vsd.x, s0); s1 = fmaf(xv3, vsd.y, s1);
            s2 = fmaf(xv3, vsd.z, s2); s3 = fmaf(xv3, vsd.w, s3);
            d0 = fmaf(xv3, vdd.x, d0); d1 = fmaf(xv3, vdd.y, d1);
            d2 = fmaf(xv3, vdd.z, d2); d3 = fmaf(xv3, vdd.w, d3);
        }
#pragma unroll
        for (int off = 4; off > 0; off >>= 1) {
            s0 += __shfl_down(s0, off, 64); s1 += __shfl_down(s1, off, 64);
            s2 += __shfl_down(s2, off, 64); s3 += __shfl_down(s3, off, 64);
            d0 += __shfl_down(d0, off, 64); d1 += __shfl_down(d1, off, 64);
            d2 += __shfl_down(d2, off, 64); d3 += __shfl_down(d3, off, 64);
        }
        if (g == 0) {
            const size_t rg = rowbase + row_l;
            *(float4*)&asrc[rg * 4] = make_float4(s0, s1, s2, s3);
            *(float4*)&adst[rg * 4] = make_float4(d0, d1, d2, d3);
        }
    }

#pragma unroll
    for (int tl = 0; tl < 2; ++tl) {
#pragma unroll
        for (int ctl = 0; ctl < 4; ++ctl) {
#pragma unroll
            for (int r = 0; r < 4; ++r) {
                const size_t rg = rowbase + tl * 16 + q * 4 + r;
                hbw[rg * 256 + (w * 4 + ctl) * 16 + i] = f2bf(acc[tl][ctl][r]);
            }
        }
    }
}

// ---------------------------------------------------------------------------
// k_scan: single-block exclusive prefix sum, 2 barriers total.
// Thread t owns nodes t*10 .. t*10+9 (1000 active threads).
// ---------------------------------------------------------------------------
__global__ __launch_bounds__(1024) void k_scan(const int* __restrict__ deg,
                                               int* __restrict__ rowptr)
{
    __shared__ int wsum[16], wexcl[16];
    const int t = threadIdx.x, wv = t >> 6, ln = t & 63;
    const int base = t * 10;
    int v[10];
    int tot = 0;
    if (base < N_) {
#pragma unroll
        for (int i = 0; i < 10; ++i) { v[i] = deg[base + i]; tot += v[i]; }
    }
    int incl = tot;
#pragma unroll
    for (int off = 1; off < 64; off <<= 1) {
        int u = __shfl_up(incl, off, 64);
        if (ln >= off) incl += u;
    }
    if (ln == 63) wsum[wv] = incl;
    __syncthreads();
    if (wv == 0 && ln < 16) {
        int s = wsum[ln];
        int si = s;
#pragma unroll
        for (int off = 1; off < 16; off <<= 1) {
            int u = __shfl_up(si, off, 64);
            if (ln >= off) si += u;
        }
        wexcl[ln] = si - s;
    }
    __syncthreads();
    if (base < N_) {
        int run = wexcl[wv] + incl - tot;
#pragma unroll
        for (int i = 0; i < 10; ++i) {
            rowptr[base + i] = run; run += v[i];
        }
    }
    if (t == 0) rowptr[N_] = E_;
}

// ---------------------------------------------------------------------------
// k_place: atomic-free counting-sort placement using precomputed rank.
// ---------------------------------------------------------------------------
__global__ __launch_bounds__(256) void k_place(
    const int* __restrict__ ei, const float* __restrict__ eattr,
    const int* __restrict__ rowptr, const int* __restrict__ rank,
    int2* __restrict__ srcea)
{
    const int e = blockIdx.x * 256 + threadIdx.x;
    if (e >= E_) return;
    const int dst = ei[E_ + e];
    const int pos = rowptr[dst] + rank[e];
    srcea[pos] = make_int2(ei[e], __float_as_int(eattr[e]));
}

// ---------------------------------------------------------------------------
// k_agg (fused edge+aggregate): one wave per (dst,b). b = blockIdx&3 gives
// XCD<->batch affinity (round-robin block->XCD => each XCD reads one 5.1 MB
// hb batch-slice ~ its L2). [R9 lesson: one-wave-per-dst/all-batches tripled
// L2 miss traffic and quartered wave count — don't.]
//   Chunk phase: lane j owns edge start+j; p=exp(leaky); per-lane denom
//   partials; (p4, hb-row base) -> LDS.
//   Inner loop: unroll-4 — 4 independent hb gathers in flight, uniform LDS
//   broadcast reads. Denominator butterfly once at end. Non-atomic out write.
// ---------------------------------------------------------------------------
__global__ __launch_bounds__(256) void k_agg(
    const int* __restrict__ rowptr, const int2* __restrict__ srcea,
    const float* __restrict__ asrc, const float* __restrict__ adst,
    const float* __restrict__ cvec, const unsigned short* __restrict__ hbu,
    const float* __restrict__ bias, float* __restrict__ out)
{
    __shared__ float pS[4][64][4];       // [wave][j][h]  4 KB
    __shared__ int   baseS[4][64];       // hb row start (ushort idx)  1 KB

    const int b    = blockIdx.x & 3;
    const int g    = blockIdx.x >> 2;
    const int wave = threadIdx.x >> 6;
    const int lane = threadIdx.x & 63;
    const int dst  = g * 4 + wave;

    const int start = rowptr[dst];
    const int end   = rowptr[dst + 1];

    const float4 ad = *(const float4*)&adst[((size_t)b * N_ + dst) * 4];
    const float4 cc = *(const float4*)cvec;

    float a0[4] = {0.f, 0.f, 0.f, 0.f};
    float a1[4] = {0.f, 0.f, 0.f, 0.f};
    float a2[4] = {0.f, 0.f, 0.f, 0.f};
    float a3[4] = {0.f, 0.f, 0.f, 0.f};
    float q0 = 0.f, q1 = 0.f, q2 = 0.f, q3 = 0.f;

    for (int c0 = start; c0 < end; c0 += 64) {
        const int jl = c0 + lane;
        const bool valid = jl < end;
        const int2 rec = srcea[valid ? jl : start];
        const int   srcl = rec.x;
        const float ea   = __int_as_float(rec.y);
        const float4 as = *(const float4*)&asrc[((size_t)b * N_ + srcl) * 4];
        float4 al;
        al.x = as.x + ad.x + ea * cc.x;
        al.y = as.y + ad.y + ea * cc.y;
        al.z = as.z + ad.z + ea * cc.z;
        al.w = as.w + ad.w + ea * cc.w;
        al.x = al.x > 0.f ? al.x : NEG_SLOPE * al.x;
        al.y = al.y > 0.f ? al.y : NEG_SLOPE * al.y;
        al.z = al.z > 0.f ? al.z : NEG_SLOPE * al.z;
        al.w = al.w > 0.f ? al.w : NEG_SLOPE * al.w;
        const float px = valid ? __expf(al.x) : 0.f;
        const float py = valid ? __expf(al.y) : 0.f;
        const float pz = valid ? __expf(al.z) : 0.f;
        const float pw = valid ? __expf(al.w) : 0.f;
        q0 += px; q1 += py; q2 += pz; q3 += pw;

        *(float4*)&pS[wave][lane][0] = make_float4(px, py, pz, pw);
        baseS[wave][lane] = ((b * N_ + srcl) << 8) + lane * 0;   // row base (ushorts)
        __builtin_amdgcn_wave_barrier();

        const int cnt = min(64, end - c0);
        const int lo4 = lane * 4;
        int j = 0;
        for (; j + 4 <= cnt; j += 4) {
            const float4 p0 = *(const float4*)&pS[wave][j + 0][0];
            const float4 p1 = *(const float4*)&pS[wave][j + 1][0];
            const float4 p2 = *(const float4*)&pS[wave][j + 2][0];
            const float4 p3 = *(const float4*)&pS[wave][j + 3][0];
            const int r0 = baseS[wave][j + 0];
            const int r1 = baseS[wave][j + 1];
            const int r2 = baseS[wave][j + 2];
            const int r3 = baseS[wave][j + 3];
            const ushort4 h0 = *(const ushort4*)&hbu[(size_t)r0 + lo4];
            const ushort4 h1 = *(const ushort4*)&hbu[(size_t)r1 + lo4];
            const ushort4 h2 = *(const ushort4*)&hbu[(size_t)r2 + lo4];
            const ushort4 h3 = *(const ushort4*)&hbu[(size_t)r3 + lo4];
            a0[0] = fmaf(p0.x, bf2f(h0.x), a0[0]);
            a0[1] = fmaf(p0.y, bf2f(h0.y), a0[1]);
            a0[2] = fmaf(p0.z, bf2f(h0.z), a0[2]);
            a0[3] = fmaf(p0.w, bf2f(h0.w), a0[3]);
            a1[0] = fmaf(p1.x, bf2f(h1.x), a1[0]);
            a1[1] = fmaf(p1.y, bf2f(h1.y), a1[1]);
            a1[2] = fmaf(p1.z, bf2f(h1.z), a1[2]);
            a1[3] = fmaf(p1.w, bf2f(h1.w), a1[3]);
            a2[0] = fmaf(p2.x, bf2f(h2.x), a2[0]);
            a2[1] = fmaf(p2.y, bf2f(h2.y), a2[1]);
            a2[2] = fmaf(p2.z, bf2f(h2.z), a2[2]);
            a2[3] = fmaf(p2.w, bf2f(h2.w), a2[3]);
            a3[0] = fmaf(p3.x, bf2f(h3.x), a3[0]);
            a3[1] = fmaf(p3.y, bf2f(h3.y), a3[1]);
            a3[2] = fmaf(p3.z, bf2f(h3.z), a3[2]);
            a3[3] = fmaf(p3.w, bf2f(h3.w), a3[3]);
        }
        for (; j < cnt; ++j) {
            const float4 p0 = *(const float4*)&pS[wave][j][0];
            const int    r0 = baseS[wave][j];
            const ushort4 h0 = *(const ushort4*)&hbu[(size_t)r0 + lo4];
            a0[0] = fmaf(p0.x, bf2f(h0.x), a0[0]);
            a0[1] = fmaf(p0.y, bf2f(h0.y), a0[1]);
            a0[2] = fmaf(p0.z, bf2f(h0.z), a0[2]);
            a0[3] = fmaf(p0.w, bf2f(h0.w), a0[3]);
        }
        __builtin_amdgcn_wave_barrier();
    }

    // denominator: butterfly reduce-all over lanes
#pragma unroll
    for (int off = 32; off > 0; off >>= 1) {
        q0 += __shfl_xor(q0, off, 64);
        q1 += __shfl_xor(q1, off, 64);
        q2 += __shfl_xor(q2, off, 64);
        q3 += __shfl_xor(q3, off, 64);
    }

    const float r = (a0[0] + a1[0] + a2[0] + a3[0]) / fmaxf(q0, 1e-16f)
                  + (a0[1] + a1[1] + a2[1] + a3[1]) / fmaxf(q1, 1e-16f)
                  + (a0[2] + a1[2] + a2[2] + a3[2]) / fmaxf(q2, 1e-16f)
                  + (a0[3] + a1[3] + a2[3] + a3[3]) / fmaxf(q3, 1e-16f);
    out[((size_t)b * N_ + dst) * O_ + lane] = 0.25f * r + bias[lane];
}

// ---------------------------------------------------------------------------
extern "C" void kernel_launch(void* const* d_in, const int* in_sizes, int n_in,
                              void* d_out, int out_size, void* d_ws, size_t ws_size,
                              hipStream_t stream)
{
    (void)in_sizes; (void)n_in; (void)out_size; (void)ws_size;
    const float* x        = (const float*)d_in[0];
    const int*   ei       = (const int*)d_in[1];     // int64 in ref -> int32 here
    const float* eattr    = (const float*)d_in[2];
    const float* Wsrc     = (const float*)d_in[3];
    const float* att_src  = (const float*)d_in[4];
    const float* att_dst  = (const float*)d_in[5];
    const float* W_edge   = (const float*)d_in[6];
    const float* att_edge = (const float*)d_in[7];
    const float* bias     = (const float*)d_in[8];
    float* out = (float*)d_out;

    // workspace carve-up (16B-aligned chunks)
    char* w = (char*)d_ws;
    auto take = [&](size_t bytes) { char* p = w; w += (bytes + 15) & ~size_t(15); return p; };
    unsigned short* hb   = (unsigned short*)take((size_t)B_ * N_ * O_ * H_ * 2); // 20.48 MB
    float* asrc    = (float*)take((size_t)B_ * N_ * H_ * 4);                     // 640 KB
    float* adst    = (float*)take((size_t)B_ * N_ * H_ * 4);
    float* c       = (float*)take(4 * 4);
    unsigned short* W1t = (unsigned short*)take((size_t)256 * 128 * 2);          // 64 KB
    unsigned short* W2t = (unsigned short*)take((size_t)256 * 128 * 2);
    float* vsrc    = (float*)take((size_t)128 * 4 * 4);                          // 2 KB
    float* vdst    = (float*)take((size_t)128 * 4 * 4);
    int* deg       = (int*)take((size_t)N_ * 4);
    int* rowptr    = (int*)take((size_t)(N_ + 1) * 4);
    int* rank      = (int*)take((size_t)E_ * 4);                                 // 640 KB
    int2* srcea    = (int2*)take((size_t)E_ * 8);                                // 1.28 MB

    hipLaunchKernelGGL(k_prep, dim3(128), dim3(256), 0, stream,
                       Wsrc, att_src, att_dst, W_edge, att_edge,
                       W1t, W2t, vsrc, vdst, deg, c);
    hipLaunchKernelGGL(k_gemm, dim3((B_ * N_) / 32), dim3(256), 0, stream,
                       x, ei, W1t, W2t, vsrc, vdst, hb, asrc, adst, deg, rank);
    hipLaunchKernelGGL(k_scan, dim3(1), dim3(1024), 0, stream, deg, rowptr);
    hipLaunchKernelGGL(k_place, dim3((E_ + 255) / 256), dim3(256), 0, stream,
                       ei, eattr, rowptr, rank, srcea);
    hipLaunchKernelGGL(k_agg, dim3(N_ / 4 * B_), dim3(256), 0, stream,
                       rowptr, srcea, asrc, adst, c, hb, bias, out);
}

// Round 11
// 169.019 us; speedup vs baseline: 1.1330x; 1.0021x over previous
//
#include <hip/hip_runtime.h>
#include <hip/hip_bf16.h>
#include <math.h>

// Problem constants (fixed shapes from the reference)
constexpr int B_  = 4;
constexpr int N_  = 10000;
constexpr int E_  = 160000;
constexpr int D_  = 128;
constexpr int H_  = 4;
constexpr int O_  = 64;
constexpr float NEG_SLOPE = 0.2f;

using short8 = __attribute__((ext_vector_type(8))) short;
using f32x4  = __attribute__((ext_vector_type(4))) float;

static __device__ __forceinline__ unsigned short f2bf(float f) {
    unsigned u = __float_as_uint(f);
    u += 0x7fffu + ((u >> 16) & 1u);           // RN-even
    return (unsigned short)(u >> 16);
}
static __device__ __forceinline__ float bf2f(unsigned short h) {
    return __uint_as_float((unsigned)h << 16);
}

// ---------------------------------------------------------------------------
// k_prep, 128 blocks:
//   block d: W1t/W2t bf16 split of Wsrc[d][h][o] -> [c][d], c = o*4+h;
//            v_src[d][h], v_dst[d][h] row reductions.
//   all blocks: grid-stride zero of deg[]; block 0: c[h].
// ---------------------------------------------------------------------------
__global__ __launch_bounds__(256) void k_prep(
    const float* __restrict__ Wsrc, const float* __restrict__ att_src,
    const float* __restrict__ att_dst,
    const float* __restrict__ W_edge, const float* __restrict__ att_edge,
    unsigned short* __restrict__ W1t, unsigned short* __restrict__ W2t,
    float* __restrict__ vsrc, float* __restrict__ vdst,
    int* __restrict__ deg, float* __restrict__ c)
{
    const int d = blockIdx.x;
    const int t = threadIdx.x;
    const int h = t >> 6;

    for (int i = d * 256 + t; i < N_; i += 128 * 256) deg[i] = 0;

    const float wv = Wsrc[(size_t)d * 256 + t];
    const unsigned short w1 = f2bf(wv);
    const unsigned short w2 = f2bf(wv - bf2f(w1));
    const int cc = ((t & 63) << 2) | h;      // o*4 + head
    W1t[(size_t)cc * 128 + d] = w1;
    W2t[(size_t)cc * 128 + d] = w2;

    float vs = wv * att_src[t];
    float vd = wv * att_dst[t];
#pragma unroll
    for (int off = 32; off > 0; off >>= 1) {
        vs += __shfl_down(vs, off, 64);
        vd += __shfl_down(vd, off, 64);
    }
    if ((t & 63) == 0) {
        vsrc[d * 4 + h] = vs;
        vdst[d * 4 + h] = vd;
    }

    if (d == 0) {
        float v = W_edge[t] * att_edge[t];
#pragma unroll
        for (int off = 32; off > 0; off >>= 1) v += __shfl_down(v, off, 64);
        if ((t & 63) == 0) c[h] = v;
    }
}

// ---------------------------------------------------------------------------
// k_gemm (MFMA) + fused dst-histogram with rank capture.
// rows = flat b*N+n (40000), cols c = o*4+head (256), K = 128.
// 32 rows/block (1250 blocks). Split-precision bf16:
// h = x1@W1 + x1@W2 + x2@W1 (fp32-accurate).
// NEW: C-store goes through an XOR-swizzled LDS buffer (reusing the A-tile
// region, barrier-separated) and exits as full-line global_store_dwordx4 —
// replaces 32 scalar 2-byte stores/thread whose 32-B-fragment write pattern
// caused store-queue backpressure (k_gemm pinned at ~52us with all pipes
// idle across R6-R10).
// ---------------------------------------------------------------------------
__global__ __launch_bounds__(256) void k_gemm(
    const float* __restrict__ x, const int* __restrict__ ei,
    const unsigned short* __restrict__ W1t, const unsigned short* __restrict__ W2t,
    const float* __restrict__ vsrc, const float* __restrict__ vdst,
    unsigned short* __restrict__ hbw, float* __restrict__ asrc, float* __restrict__ adst,
    int* __restrict__ deg, int* __restrict__ rank)
{
    constexpr int ROWS = 32;
    constexpr int APAD = 136;                // ushort stride (128+8)
    __shared__ uint4 SHq[1088];              // 17408 B: A1+A2, later C-buffer
    __shared__ float4 vsL[128];
    __shared__ float4 vdL[128];
    unsigned short* A1 = (unsigned short*)SHq;            // 32*136 = 4352
    unsigned short* A2 = A1 + ROWS * APAD;                // 32*136 = 4352
    unsigned short* Cb = (unsigned short*)SHq;            // 32*256 = 8192 (reuse)

    const int t = threadIdx.x;
    const int w = t >> 6;
    const int lane = t & 63;
    const int i = lane & 15;
    const int q = lane >> 4;
    const size_t rowbase = (size_t)blockIdx.x * ROWS;

    // fused histogram + rank: 128 edges per block
    if (t < 128) {
        const int ee = blockIdx.x * 128 + t;
        rank[ee] = atomicAdd(&deg[ei[E_ + ee]], 1);
    }

    {
        const float4* xg = (const float4*)(x + rowbase * D_);
#pragma unroll
        for (int it = 0; it < 4; ++it) {
            const int idx = it * 256 + t;
            const int row = idx >> 5;
            const int c4  = idx & 31;
            float4 xv = xg[idx];
            ushort4 h1, h2;
            h1.x = f2bf(xv.x); h2.x = f2bf(xv.x - bf2f(h1.x));
            h1.y = f2bf(xv.y); h2.y = f2bf(xv.y - bf2f(h1.y));
            h1.z = f2bf(xv.z); h2.z = f2bf(xv.z - bf2f(h1.z));
            h1.w = f2bf(xv.w); h2.w = f2bf(xv.w - bf2f(h1.w));
            *(ushort4*)&A1[row * APAD + c4 * 4] = h1;
            *(ushort4*)&A2[row * APAD + c4 * 4] = h2;
        }
        if (t < 128) vsL[t] = ((const float4*)vsrc)[t];
        else         vdL[t - 128] = ((const float4*)vdst)[t - 128];
    }
    __syncthreads();

    f32x4 acc[2][4];
#pragma unroll
    for (int tl = 0; tl < 2; ++tl)
#pragma unroll
        for (int ctl = 0; ctl < 4; ++ctl) acc[tl][ctl] = (f32x4){0.f, 0.f, 0.f, 0.f};

#pragma unroll
    for (int ks = 0; ks < 4; ++ks) {
        const int a0off = i * APAD + ks * 32 + q * 8;
        const int a1off = (16 + i) * APAD + ks * 32 + q * 8;
        short8 a1t0 = *(const short8*)&A1[a0off];
        short8 a2t0 = *(const short8*)&A2[a0off];
        short8 a1t1 = *(const short8*)&A1[a1off];
        short8 a2t1 = *(const short8*)&A2[a1off];

        short8 b1[4], b2[4];
#pragma unroll
        for (int ctl = 0; ctl < 4; ++ctl) {
            const size_t boff = (size_t)((w * 4 + ctl) * 16 + i) * 128 + ks * 32 + q * 8;
            b1[ctl] = *(const short8*)&W1t[boff];
            b2[ctl] = *(const short8*)&W2t[boff];
        }
#pragma unroll
        for (int ctl = 0; ctl < 4; ++ctl) {
            acc[0][ctl] = __builtin_amdgcn_mfma_f32_16x16x32_bf16(a1t0, b1[ctl], acc[0][ctl], 0, 0, 0);
            acc[0][ctl] = __builtin_amdgcn_mfma_f32_16x16x32_bf16(a2t0, b1[ctl], acc[0][ctl], 0, 0, 0);
            acc[0][ctl] = __builtin_amdgcn_mfma_f32_16x16x32_bf16(a1t0, b2[ctl], acc[0][ctl], 0, 0, 0);
            acc[1][ctl] = __builtin_amdgcn_mfma_f32_16x16x32_bf16(a1t1, b1[ctl], acc[1][ctl], 0, 0, 0);
            acc[1][ctl] = __builtin_amdgcn_mfma_f32_16x16x32_bf16(a2t1, b1[ctl], acc[1][ctl], 0, 0, 0);
            acc[1][ctl] = __builtin_amdgcn_mfma_f32_16x16x32_bf16(a1t1, b2[ctl], acc[1][ctl], 0, 0, 0);
        }
    }

    {   // epilogue 1: exact a_src/a_dst from (A1+A2) . v
        const int r = lane >> 3, g = lane & 7;
        const int row_l = w * 8 + r;
        float s0 = 0, s1 = 0, s2 = 0, s3 = 0, d0 = 0, d1 = 0, d2 = 0, d3 = 0;
#pragma unroll
        for (int dd4 = 0; dd4 < 4; ++dd4) {
            const int db = g * 16 + dd4 * 4;
            ushort4 u1 = *(const ushort4*)&A1[row_l * APAD + db];
            ushort4 u2 = *(const ushort4*)&A2[row_l * APAD + db];
            const float xv0 = bf2f(u1.x) + bf2f(u2.x);
            const float xv1 = bf2f(u1.y) + bf2f(u2.y);
            const float xv2 = bf2f(u1.z) + bf2f(u2.z);
            const float xv3 = bf2f(u1.w) + bf2f(u2.w);
            float4 vsa = vsL[db + 0], vda = vdL[db + 0];
            float4 vsb = vsL[db + 1], vdb = vdL[db + 1];
            float4 vsc = vsL[db + 2], vdc = vdL[db + 2];
            float4 vsd = vsL[db + 3], vdd = vdL[db + 3];
            s0 = fmaf(xv0, vsa.x, s0); s1 = fmaf(xv0, vsa.y, s1);
            s2 = fmaf(xv0, vsa.z, s2); s3 = fmaf(xv0, vsa.w, s3);
            d0 = fmaf(xv0, vda.x, d0); d1 = fmaf(xv0, vda.y, d1);
            d2 = fmaf(xv0, vda.z, d2); d3 = fmaf(xv0, vda.w, d3);
            s0 = fmaf(xv1, vsb.x, s0); s1 = fmaf(xv1, vsb.y, s1);
            s2 = fmaf(xv1, vsb.z, s2); s3 = fmaf(xv1, vsb.w, s3);
            d0 = fmaf(xv1, vdb.x, d0); d1 = fmaf(xv1, vdb.y, d1);
            d2 = fmaf(xv1, vdb.z, d2); d3 = fmaf(xv1, vdb.w, d3);
            s0 = fmaf(xv2, vsc.x, s0); s1 = fmaf(xv2, vsc.y, s1);
            s2 = fmaf(xv2, vsc.z, s2); s3 = fmaf(xv2, vsc.w, s3);
            d0 = fmaf(xv2, vdc.x, d0); d1 = fmaf(xv2, vdc.y, d1);
            d2 = fmaf(xv2, vdc.z, d2); d3 = fmaf(xv2, vdc.w, d3);
            s0 = fmaf(xv3, vsd.x, s0); s1 = fmaf(xv3, vsd.y, s1);
            s2 = fmaf(xv3, vsd.z, s2); s3 = fmaf(xv3, vsd.w, s3);
            d0 = fmaf(xv3, vdd.x, d0); d1 = fmaf(xv3, vdd.y, d1);
            d2 = fmaf(xv3, vdd.z, d2); d3 = fmaf(xv3, vdd.w, d3);
        }
#pragma unroll
        for (int off = 4; off > 0; off >>= 1) {
            s0 += __shfl_down(s0, off, 64); s1 += __shfl_down(s1, off, 64);
            s2 += __shfl_down(s2, off, 64); s3 += __shfl_down(s3, off, 64);
            d0 += __shfl_down(d0, off, 64); d1 += __shfl_down(d1, off, 64);
            d2 += __shfl_down(d2, off, 64); d3 += __shfl_down(d3, off, 64);
        }
        if (g == 0) {
            const size_t rg = rowbase + row_l;
            *(float4*)&asrc[rg * 4] = make_float4(s0, s1, s2, s3);
            *(float4*)&adst[rg * 4] = make_float4(d0, d1, d2, d3);
        }
    }

    // ---- epilogue 2: C via XOR-swizzled LDS, then full-line stores ----
    __syncthreads();                         // A1/A2 dead; reuse as Cb
#pragma unroll
    for (int tl = 0; tl < 2; ++tl) {
#pragma unroll
        for (int ctl = 0; ctl < 4; ++ctl) {
            const int col = (w * 4 + ctl) * 16 + i;      // 0..255
            const int chnk = col >> 3;                   // 16B chunk 0..31
            const int within = col & 7;
#pragma unroll
            for (int r = 0; r < 4; ++r) {
                const int row = tl * 16 + q * 4 + r;     // 0..31
                const int s = chnk ^ row;                // swizzle (row&31 = row)
                Cb[row * 256 + s * 8 + within] = f2bf(acc[tl][ctl][r]);
            }
        }
    }
    __syncthreads();
    {
        const int chnk = t & 31;
#pragma unroll
        for (int k = 0; k < 4; ++k) {
            const int row = k * 8 + (t >> 5);
            const int s = chnk ^ row;
            const uint4 v = *(const uint4*)&Cb[row * 256 + s * 8];
            *(uint4*)&hbw[(rowbase + row) * 256 + chnk * 8] = v;
        }
    }
}

// ---------------------------------------------------------------------------
// k_scan: single-block exclusive prefix sum, 2 barriers total.
// Thread t owns nodes t*10 .. t*10+9 (1000 active threads).
// ---------------------------------------------------------------------------
__global__ __launch_bounds__(1024) void k_scan(const int* __restrict__ deg,
                                               int* __restrict__ rowptr)
{
    __shared__ int wsum[16], wexcl[16];
    const int t = threadIdx.x, wv = t >> 6, ln = t & 63;
    const int base = t * 10;
    int v[10];
    int tot = 0;
    if (base < N_) {
#pragma unroll
        for (int i = 0; i < 10; ++i) { v[i] = deg[base + i]; tot += v[i]; }
    }
    int incl = tot;
#pragma unroll
    for (int off = 1; off < 64; off <<= 1) {
        int u = __shfl_up(incl, off, 64);
        if (ln >= off) incl += u;
    }
    if (ln == 63) wsum[wv] = incl;
    __syncthreads();
    if (wv == 0 && ln < 16) {
        int s = wsum[ln];
        int si = s;
#pragma unroll
        for (int off = 1; off < 16; off <<= 1) {
            int u = __shfl_up(si, off, 64);
            if (ln >= off) si += u;
        }
        wexcl[ln] = si - s;
    }
    __syncthreads();
    if (base < N_) {
        int run = wexcl[wv] + incl - tot;
#pragma unroll
        for (int i = 0; i < 10; ++i) {
            rowptr[base + i] = run; run += v[i];
        }
    }
    if (t == 0) rowptr[N_] = E_;
}

// ---------------------------------------------------------------------------
// k_place: atomic-free counting-sort placement using precomputed rank.
// ---------------------------------------------------------------------------
__global__ __launch_bounds__(256) void k_place(
    const int* __restrict__ ei, const float* __restrict__ eattr,
    const int* __restrict__ rowptr, const int* __restrict__ rank,
    int2* __restrict__ srcea)
{
    const int e = blockIdx.x * 256 + threadIdx.x;
    if (e >= E_) return;
    const int dst = ei[E_ + e];
    const int pos = rowptr[dst] + rank[e];
    srcea[pos] = make_int2(ei[e], __float_as_int(eattr[e]));
}

// ---------------------------------------------------------------------------
// k_agg (fused edge+aggregate): one wave per (dst,b). b = blockIdx&3 gives
// XCD<->batch affinity. [R9 lesson: one-wave-per-dst/all-batches tripled
// L2 miss traffic and quartered wave count — don't.]
//   Chunk phase: lane j owns edge start+j; p=exp(leaky); per-lane denom
//   partials; (p4, hb-row base) -> LDS.
//   Inner loop: unroll-4 — 4 independent hb gathers in flight, uniform LDS
//   broadcast reads. Denominator butterfly once at end. Non-atomic out write.
// ---------------------------------------------------------------------------
__global__ __launch_bounds__(256) void k_agg(
    const int* __restrict__ rowptr, const int2* __restrict__ srcea,
    const float* __restrict__ asrc, const float* __restrict__ adst,
    const float* __restrict__ cvec, const unsigned short* __restrict__ hbu,
    const float* __restrict__ bias, float* __restrict__ out)
{
    __shared__ float pS[4][64][4];       // [wave][j][h]  4 KB
    __shared__ int   baseS[4][64];       // hb row start (ushort idx)  1 KB

    const int b    = blockIdx.x & 3;
    const int g    = blockIdx.x >> 2;
    const int wave = threadIdx.x >> 6;
    const int lane = threadIdx.x & 63;
    const int dst  = g * 4 + wave;

    const int start = rowptr[dst];
    const int end   = rowptr[dst + 1];

    const float4 ad = *(const float4*)&adst[((size_t)b * N_ + dst) * 4];
    const float4 cc = *(const float4*)cvec;

    float a0[4] = {0.f, 0.f, 0.f, 0.f};
    float a1[4] = {0.f, 0.f, 0.f, 0.f};
    float a2[4] = {0.f, 0.f, 0.f, 0.f};
    float a3[4] = {0.f, 0.f, 0.f, 0.f};
    float q0 = 0.f, q1 = 0.f, q2 = 0.f, q3 = 0.f;

    for (int c0 = start; c0 < end; c0 += 64) {
        const int jl = c0 + lane;
        const bool valid = jl < end;
        const int2 rec = srcea[valid ? jl : start];
        const int   srcl = rec.x;
        const float ea   = __int_as_float(rec.y);
        const float4 as = *(const float4*)&asrc[((size_t)b * N_ + srcl) * 4];
        float4 al;
        al.x = as.x + ad.x + ea * cc.x;
        al.y = as.y + ad.y + ea * cc.y;
        al.z = as.z + ad.z + ea * cc.z;
        al.w = as.w + ad.w + ea * cc.w;
        al.x = al.x > 0.f ? al.x : NEG_SLOPE * al.x;
        al.y = al.y > 0.f ? al.y : NEG_SLOPE * al.y;
        al.z = al.z > 0.f ? al.z : NEG_SLOPE * al.z;
        al.w = al.w > 0.f ? al.w : NEG_SLOPE * al.w;
        const float px = valid ? __expf(al.x) : 0.f;
        const float py = valid ? __expf(al.y) : 0.f;
        const float pz = valid ? __expf(al.z) : 0.f;
        const float pw = valid ? __expf(al.w) : 0.f;
        q0 += px; q1 += py; q2 += pz; q3 += pw;

        *(float4*)&pS[wave][lane][0] = make_float4(px, py, pz, pw);
        baseS[wave][lane] = (b * N_ + srcl) << 8;        // row base (ushorts)
        __builtin_amdgcn_wave_barrier();

        const int cnt = min(64, end - c0);
        const int lo4 = lane * 4;
        int j = 0;
        for (; j + 4 <= cnt; j += 4) {
            const float4 p0 = *(const float4*)&pS[wave][j + 0][0];
            const float4 p1 = *(const float4*)&pS[wave][j + 1][0];
            const float4 p2 = *(const float4*)&pS[wave][j + 2][0];
            const float4 p3 = *(const float4*)&pS[wave][j + 3][0];
            const int r0 = baseS[wave][j + 0];
            const int r1 = baseS[wave][j + 1];
            const int r2 = baseS[wave][j + 2];
            const int r3 = baseS[wave][j + 3];
            const ushort4 h0 = *(const ushort4*)&hbu[(size_t)r0 + lo4];
            const ushort4 h1 = *(const ushort4*)&hbu[(size_t)r1 + lo4];
            const ushort4 h2 = *(const ushort4*)&hbu[(size_t)r2 + lo4];
            const ushort4 h3 = *(const ushort4*)&hbu[(size_t)r3 + lo4];
            a0[0] = fmaf(p0.x, bf2f(h0.x), a0[0]);
            a0[1] = fmaf(p0.y, bf2f(h0.y), a0[1]);
            a0[2] = fmaf(p0.z, bf2f(h0.z), a0[2]);
            a0[3] = fmaf(p0.w, bf2f(h0.w), a0[3]);
            a1[0] = fmaf(p1.x, bf2f(h1.x), a1[0]);
            a1[1] = fmaf(p1.y, bf2f(h1.y), a1[1]);
            a1[2] = fmaf(p1.z, bf2f(h1.z), a1[2]);
            a1[3] = fmaf(p1.w, bf2f(h1.w), a1[3]);
            a2[0] = fmaf(p2.x, bf2f(h2.x), a2[0]);
            a2[1] = fmaf(p2.y, bf2f(h2.y), a2[1]);
            a2[2] = fmaf(p2.z, bf2f(h2.z), a2[2]);
            a2[3] = fmaf(p2.w, bf2f(h2.w), a2[3]);
            a3[0] = fmaf(p3.x, bf2f(h3.x), a3[0]);
            a3[1] = fmaf(p3.y, bf2f(h3.y), a3[1]);
            a3[2] = fmaf(p3.z, bf2f(h3.z), a3[2]);
            a3[3] = fmaf(p3.w, bf2f(h3.w), a3[3]);
        }
        for (; j < cnt; ++j) {
            const float4 p0 = *(const float4*)&pS[wave][j][0];
            const int    r0 = baseS[wave][j];
            const ushort4 h0 = *(const ushort4*)&hbu[(size_t)r0 + lo4];
            a0[0] = fmaf(p0.x, bf2f(h0.x), a0[0]);
            a0[1] = fmaf(p0.y, bf2f(h0.y), a0[1]);
            a0[2] = fmaf(p0.z, bf2f(h0.z), a0[2]);
            a0[3] = fmaf(p0.w, bf2f(h0.w), a0[3]);
        }
        __builtin_amdgcn_wave_barrier();
    }

    // denominator: butterfly reduce-all over lanes
#pragma unroll
    for (int off = 32; off > 0; off >>= 1) {
        q0 += __shfl_xor(q0, off, 64);
        q1 += __shfl_xor(q1, off, 64);
        q2 += __shfl_xor(q2, off, 64);
        q3 += __shfl_xor(q3, off, 64);
    }

    const float r = (a0[0] + a1[0] + a2[0] + a3[0]) / fmaxf(q0, 1e-16f)
                  + (a0[1] + a1[1] + a2[1] + a3[1]) / fmaxf(q1, 1e-16f)
                  + (a0[2] + a1[2] + a2[2] + a3[2]) / fmaxf(q2, 1e-16f)
                  + (a0[3] + a1[3] + a2[3] + a3[3]) / fmaxf(q3, 1e-16f);
    out[((size_t)b * N_ + dst) * O_ + lane] = 0.25f * r + bias[lane];
}

// ---------------------------------------------------------------------------
extern "C" void kernel_launch(void* const* d_in, const int* in_sizes, int n_in,
                              void* d_out, int out_size, void* d_ws, size_t ws_size,
                              hipStream_t stream)
{
    (void)in_sizes; (void)n_in; (void)out_size; (void)ws_size;
    const float* x        = (const float*)d_in[0];
    const int*   ei       = (const int*)d_in[1];     // int64 in ref -> int32 here
    const float* eattr    = (const float*)d_in[2];
    const float* Wsrc     = (const float*)d_in[3];
    const float* att_src  = (const float*)d_in[4];
    const float* att_dst  = (const float*)d_in[5];
    const float* W_edge   = (const float*)d_in[6];
    const float* att_edge = (const float*)d_in[7];
    const float* bias     = (const float*)d_in[8];
    float* out = (float*)d_out;

    // workspace carve-up (16B-aligned chunks)
    char* w = (char*)d_ws;
    auto take = [&](size_t bytes) { char* p = w; w += (bytes + 15) & ~size_t(15); return p; };
    unsigned short* hb   = (unsigned short*)take((size_t)B_ * N_ * O_ * H_ * 2); // 20.48 MB
    float* asrc    = (float*)take((size_t)B_ * N_ * H_ * 4);                     // 640 KB
    float* adst    = (float*)take((size_t)B_ * N_ * H_ * 4);
    float* c       = (float*)take(4 * 4);
    unsigned short* W1t = (unsigned short*)take((size_t)256 * 128 * 2);          // 64 KB
    unsigned short* W2t = (unsigned short*)take((size_t)256 * 128 * 2);
    float* vsrc    = (float*)take((size_t)128 * 4 * 4);                          // 2 KB
    float* vdst    = (float*)take((size_t)128 * 4 * 4);
    int* deg       = (int*)take((size_t)N_ * 4);
    int* rowptr    = (int*)take((size_t)(N_ + 1) * 4);
    int* rank      = (int*)take((size_t)E_ * 4);                                 // 640 KB
    int2* srcea    = (int2*)take((size_t)E_ * 8);                                // 1.28 MB

    hipLaunchKernelGGL(k_prep, dim3(128), dim3(256), 0, stream,
                       Wsrc, att_src, att_dst, W_edge, att_edge,
                       W1t, W2t, vsrc, vdst, deg, c);
    hipLaunchKernelGGL(k_gemm, dim3((B_ * N_) / 32), dim3(256), 0, stream,
                       x, ei, W1t, W2t, vsrc, vdst, hb, asrc, adst, deg, rank);
    hipLaunchKernelGGL(k_scan, dim3(1), dim3(1024), 0, stream, deg, rowptr);
    hipLaunchKernelGGL(k_place, dim3((E_ + 255) / 256), dim3(256), 0, stream,
                       ei, eattr, rowptr, rank, srcea);
    hipLaunchKernelGGL(k_agg, dim3(N_ / 4 * B_), dim3(256), 0, stream,
                       rowptr, srcea, asrc, adst, c, hb, bias, out);
}

// Round 12
// 160.224 us; speedup vs baseline: 1.1952x; 1.0549x over previous
//
#include <hip/hip_runtime.h>
#include <hip/hip_bf16.h>
#include <math.h>

// Problem constants (fixed shapes from the reference)
constexpr int B_  = 4;
constexpr int N_  = 10000;
constexpr int E_  = 160000;
constexpr int D_  = 128;
constexpr int H_  = 4;
constexpr int O_  = 64;
constexpr float NEG_SLOPE = 0.2f;

using short8 = __attribute__((ext_vector_type(8))) short;
using f32x4  = __attribute__((ext_vector_type(4))) float;

static __device__ __forceinline__ unsigned short f2bf(float f) {
    unsigned u = __float_as_uint(f);
    u += 0x7fffu + ((u >> 16) & 1u);           // RN-even
    return (unsigned short)(u >> 16);
}
static __device__ __forceinline__ float bf2f(unsigned short h) {
    return __uint_as_float((unsigned)h << 16);
}

// ---------------------------------------------------------------------------
// k_prep, 128 blocks:
//   block d: W1t bf16 of Wsrc[d][h][o] -> [c][d], c = o*4+h (B-operand layout)
//            v_src[d][h], v_dst[d][h] row reductions.
//   all blocks: grid-stride zero of deg[]; block 0: c[h].
// ---------------------------------------------------------------------------
__global__ __launch_bounds__(256) void k_prep(
    const float* __restrict__ Wsrc, const float* __restrict__ att_src,
    const float* __restrict__ att_dst,
    const float* __restrict__ W_edge, const float* __restrict__ att_edge,
    unsigned short* __restrict__ W1t,
    float* __restrict__ vsrc, float* __restrict__ vdst,
    int* __restrict__ deg, float* __restrict__ c)
{
    const int d = blockIdx.x;
    const int t = threadIdx.x;
    const int h = t >> 6;

    for (int i = d * 256 + t; i < N_; i += 128 * 256) deg[i] = 0;

    const float wv = Wsrc[(size_t)d * 256 + t];
    const int cc = ((t & 63) << 2) | h;      // o*4 + head
    W1t[(size_t)cc * 128 + d] = f2bf(wv);

    float vs = wv * att_src[t];
    float vd = wv * att_dst[t];
#pragma unroll
    for (int off = 32; off > 0; off >>= 1) {
        vs += __shfl_down(vs, off, 64);
        vd += __shfl_down(vd, off, 64);
    }
    if ((t & 63) == 0) {
        vsrc[d * 4 + h] = vs;
        vdst[d * 4 + h] = vd;
    }

    if (d == 0) {
        float v = W_edge[t] * att_edge[t];
#pragma unroll
        for (int off = 32; off > 0; off >>= 1) v += __shfl_down(v, off, 64);
        if ((t & 63) == 0) c[h] = v;
    }
}

// ---------------------------------------------------------------------------
// k_gemm (MFMA), latency-chain restructure (R11 postmortem: ~40 of 50us was
// dependency latency, not any pipe):
//  - single bf16 path (no error-split): 32 MFMA/wave instead of 96, half the
//    staging conversions (absmax budget: +~1.4e-3 sigma input rounding on top
//    of the 2^-7 bf16 store quantum; threshold 0.0233 has room)
//  - ALL 16 B-fragments prefetched into registers BEFORE the staging barrier
//    (B-load latency overlaps x-load; MFMA loop is pure ds_read+MFMA)
//  - fused hist/rank atomic moved to kernel END so its L2 round trip no
//    longer gates the compiler's vmcnt(0)-before-s_barrier drains.
// rows = flat b*N+n (40000), cols c = o*4+head (256), K = 128. 32 rows/block.
// ---------------------------------------------------------------------------
__global__ __launch_bounds__(256) void k_gemm(
    const float* __restrict__ x, const int* __restrict__ ei,
    const unsigned short* __restrict__ W1t,
    const float* __restrict__ vsrc, const float* __restrict__ vdst,
    unsigned short* __restrict__ hbw, float* __restrict__ asrc, float* __restrict__ adst,
    int* __restrict__ deg, int* __restrict__ rank)
{
    constexpr int ROWS = 32;
    constexpr int APAD = 136;                // ushort stride (128+8)
    __shared__ uint4 SHq[1024];              // 16384 B: A1 (8704) then Cb (16384)
    __shared__ float4 vsL[128];
    __shared__ float4 vdL[128];
    unsigned short* A1 = (unsigned short*)SHq;
    unsigned short* Cb = (unsigned short*)SHq;

    const int t = threadIdx.x;
    const int w = t >> 6;
    const int lane = t & 63;
    const int i = lane & 15;
    const int q = lane >> 4;
    const size_t rowbase = (size_t)blockIdx.x * ROWS;

    // ---- prefetch all B fragments into registers (16 independent loads) ----
    short8 breg[4][4];                       // [ks][ctl]
#pragma unroll
    for (int ks = 0; ks < 4; ++ks)
#pragma unroll
        for (int ctl = 0; ctl < 4; ++ctl) {
            const size_t boff = (size_t)((w * 4 + ctl) * 16 + i) * 128 + ks * 32 + q * 8;
            breg[ks][ctl] = *(const short8*)&W1t[boff];
        }

    // ---- stage x -> bf16 in LDS (+ v vectors) ----
    {
        const float4* xg = (const float4*)(x + rowbase * D_);
#pragma unroll
        for (int it = 0; it < 4; ++it) {
            const int idx = it * 256 + t;    // 1024 float4 = 32 rows x 32
            const int row = idx >> 5;
            const int c4  = idx & 31;
            float4 xv = xg[idx];
            ushort4 h1;
            h1.x = f2bf(xv.x); h1.y = f2bf(xv.y);
            h1.z = f2bf(xv.z); h1.w = f2bf(xv.w);
            *(ushort4*)&A1[row * APAD + c4 * 4] = h1;
        }
        if (t < 128) vsL[t] = ((const float4*)vsrc)[t];
        else         vdL[t - 128] = ((const float4*)vdst)[t - 128];
    }
    __syncthreads();

    // ---- MFMA main loop: pure ds_read + MFMA (B already in registers) ----
    f32x4 acc[2][4];
#pragma unroll
    for (int tl = 0; tl < 2; ++tl)
#pragma unroll
        for (int ctl = 0; ctl < 4; ++ctl) acc[tl][ctl] = (f32x4){0.f, 0.f, 0.f, 0.f};

#pragma unroll
    for (int ks = 0; ks < 4; ++ks) {
        const int a0off = i * APAD + ks * 32 + q * 8;
        const int a1off = (16 + i) * APAD + ks * 32 + q * 8;
        short8 at0 = *(const short8*)&A1[a0off];
        short8 at1 = *(const short8*)&A1[a1off];
#pragma unroll
        for (int ctl = 0; ctl < 4; ++ctl) {
            acc[0][ctl] = __builtin_amdgcn_mfma_f32_16x16x32_bf16(at0, breg[ks][ctl], acc[0][ctl], 0, 0, 0);
            acc[1][ctl] = __builtin_amdgcn_mfma_f32_16x16x32_bf16(at1, breg[ks][ctl], acc[1][ctl], 0, 0, 0);
        }
    }

    {   // epilogue 1: a_src/a_dst from bf16(x) . v  (alpha err ~1e-3, benign)
        const int r = lane >> 3, g = lane & 7;
        const int row_l = w * 8 + r;
        float s0 = 0, s1 = 0, s2 = 0, s3 = 0, d0 = 0, d1 = 0, d2 = 0, d3 = 0;
#pragma unroll
        for (int dd4 = 0; dd4 < 4; ++dd4) {
            const int db = g * 16 + dd4 * 4;
            ushort4 u1 = *(const ushort4*)&A1[row_l * APAD + db];
            const float xv0 = bf2f(u1.x);
            const float xv1 = bf2f(u1.y);
            const float xv2 = bf2f(u1.z);
            const float xv3 = bf2f(u1.w);
            float4 vsa = vsL[db + 0], vda = vdL[db + 0];
            float4 vsb = vsL[db + 1], vdb = vdL[db + 1];
            float4 vsc = vsL[db + 2], vdc = vdL[db + 2];
            float4 vsd = vsL[db + 3], vdd = vdL[db + 3];
            s0 = fmaf(xv0, vsa.x, s0); s1 = fmaf(xv0, vsa.y, s1);
            s2 = fmaf(xv0, vsa.z, s2); s3 = fmaf(xv0, vsa.w, s3);
            d0 = fmaf(xv0, vda.x, d0); d1 = fmaf(xv0, vda.y, d1);
            d2 = fmaf(xv0, vda.z, d2); d3 = fmaf(xv0, vda.w, d3);
            s0 = fmaf(xv1, vsb.x, s0); s1 = fmaf(xv1, vsb.y, s1);
            s2 = fmaf(xv1, vsb.z, s2); s3 = fmaf(xv1, vsb.w, s3);
            d0 = fmaf(xv1, vdb.x, d0); d1 = fmaf(xv1, vdb.y, d1);
            d2 = fmaf(xv1, vdb.z, d2); d3 = fmaf(xv1, vdb.w, d3);
            s0 = fmaf(xv2, vsc.x, s0); s1 = fmaf(xv2, vsc.y, s1);
            s2 = fmaf(xv2, vsc.z, s2); s3 = fmaf(xv2, vsc.w, s3);
            d0 = fmaf(xv2, vdc.x, d0); d1 = fmaf(xv2, vdc.y, d1);
            d2 = fmaf(xv2, vdc.z, d2); d3 = fmaf(xv2, vdc.w, d3);
            s0 = fmaf(xv3, vsd.x, s0); s1 = fmaf(xv3, vsd.y, s1);
            s2 = fmaf(xv3, vsd.z, s2); s3 = fmaf(xv3, vsd.w, s3);
            d0 = fmaf(xv3, vdd.x, d0); d1 = fmaf(xv3, vdd.y, d1);
            d2 = fmaf(xv3, vdd.z, d2); d3 = fmaf(xv3, vdd.w, d3);
        }
#pragma unroll
        for (int off = 4; off > 0; off >>= 1) {
            s0 += __shfl_down(s0, off, 64); s1 += __shfl_down(s1, off, 64);
            s2 += __shfl_down(s2, off, 64); s3 += __shfl_down(s3, off, 64);
            d0 += __shfl_down(d0, off, 64); d1 += __shfl_down(d1, off, 64);
            d2 += __shfl_down(d2, off, 64); d3 += __shfl_down(d3, off, 64);
        }
        if (g == 0) {
            const size_t rg = rowbase + row_l;
            *(float4*)&asrc[rg * 4] = make_float4(s0, s1, s2, s3);
            *(float4*)&adst[rg * 4] = make_float4(d0, d1, d2, d3);
        }
    }

    // ---- epilogue 2: C via XOR-swizzled LDS, full-line stores ----
    __syncthreads();                         // A1 dead; reuse as Cb
#pragma unroll
    for (int tl = 0; tl < 2; ++tl) {
#pragma unroll
        for (int ctl = 0; ctl < 4; ++ctl) {
            const int col = (w * 4 + ctl) * 16 + i;      // 0..255
            const int chnk = col >> 3;                   // 16B chunk 0..31
            const int within = col & 7;
#pragma unroll
            for (int r = 0; r < 4; ++r) {
                const int row = tl * 16 + q * 4 + r;     // 0..31
                const int s = chnk ^ row;
                Cb[row * 256 + s * 8 + within] = f2bf(acc[tl][ctl][r]);
            }
        }
    }
    __syncthreads();
    {
        const int chnk = t & 31;
#pragma unroll
        for (int k = 0; k < 4; ++k) {
            const int row = k * 8 + (t >> 5);
            const int s = chnk ^ row;
            const uint4 v = *(const uint4*)&Cb[row * 256 + s * 8];
            *(uint4*)&hbw[(rowbase + row) * 256 + chnk * 8] = v;
        }
    }

    // ---- fused histogram + rank at kernel END (no barrier after) ----
    if (t < 128) {
        const int ee = blockIdx.x * 128 + t;
        rank[ee] = atomicAdd(&deg[ei[E_ + ee]], 1);
    }
}

// ---------------------------------------------------------------------------
// k_scan: single-block exclusive prefix sum, 2 barriers total.
// Thread t owns nodes t*10 .. t*10+9 (1000 active threads).
// ---------------------------------------------------------------------------
__global__ __launch_bounds__(1024) void k_scan(const int* __restrict__ deg,
                                               int* __restrict__ rowptr)
{
    __shared__ int wsum[16], wexcl[16];
    const int t = threadIdx.x, wv = t >> 6, ln = t & 63;
    const int base = t * 10;
    int v[10];
    int tot = 0;
    if (base < N_) {
#pragma unroll
        for (int i = 0; i < 10; ++i) { v[i] = deg[base + i]; tot += v[i]; }
    }
    int incl = tot;
#pragma unroll
    for (int off = 1; off < 64; off <<= 1) {
        int u = __shfl_up(incl, off, 64);
        if (ln >= off) incl += u;
    }
    if (ln == 63) wsum[wv] = incl;
    __syncthreads();
    if (wv == 0 && ln < 16) {
        int s = wsum[ln];
        int si = s;
#pragma unroll
        for (int off = 1; off < 16; off <<= 1) {
            int u = __shfl_up(si, off, 64);
            if (ln >= off) si += u;
        }
        wexcl[ln] = si - s;
    }
    __syncthreads();
    if (base < N_) {
        int run = wexcl[wv] + incl - tot;
#pragma unroll
        for (int i = 0; i < 10; ++i) {
            rowptr[base + i] = run; run += v[i];
        }
    }
    if (t == 0) rowptr[N_] = E_;
}

// ---------------------------------------------------------------------------
// k_place: atomic-free counting-sort placement using precomputed rank.
// ---------------------------------------------------------------------------
__global__ __launch_bounds__(256) void k_place(
    const int* __restrict__ ei, const float* __restrict__ eattr,
    const int* __restrict__ rowptr, const int* __restrict__ rank,
    int2* __restrict__ srcea)
{
    const int e = blockIdx.x * 256 + threadIdx.x;
    if (e >= E_) return;
    const int dst = ei[E_ + e];
    const int pos = rowptr[dst] + rank[e];
    srcea[pos] = make_int2(ei[e], __float_as_int(eattr[e]));
}

// ---------------------------------------------------------------------------
// k_agg (fused edge+aggregate): one wave per (dst,b). b = blockIdx&3 gives
// XCD<->batch affinity. [R9 lesson: one-wave-per-dst/all-batches tripled
// L2 miss traffic and quartered wave count — don't.]
// ---------------------------------------------------------------------------
__global__ __launch_bounds__(256) void k_agg(
    const int* __restrict__ rowptr, const int2* __restrict__ srcea,
    const float* __restrict__ asrc, const float* __restrict__ adst,
    const float* __restrict__ cvec, const unsigned short* __restrict__ hbu,
    const float* __restrict__ bias, float* __restrict__ out)
{
    __shared__ float pS[4][64][4];       // [wave][j][h]  4 KB
    __shared__ int   baseS[4][64];       // hb row start (ushort idx)  1 KB

    const int b    = blockIdx.x & 3;
    const int g    = blockIdx.x >> 2;
    const int wave = threadIdx.x >> 6;
    const int lane = threadIdx.x & 63;
    const int dst  = g * 4 + wave;

    const int start = rowptr[dst];
    const int end   = rowptr[dst + 1];

    const float4 ad = *(const float4*)&adst[((size_t)b * N_ + dst) * 4];
    const float4 cc = *(const float4*)cvec;

    float a0[4] = {0.f, 0.f, 0.f, 0.f};
    float a1[4] = {0.f, 0.f, 0.f, 0.f};
    float a2[4] = {0.f, 0.f, 0.f, 0.f};
    float a3[4] = {0.f, 0.f, 0.f, 0.f};
    float q0 = 0.f, q1 = 0.f, q2 = 0.f, q3 = 0.f;

    for (int c0 = start; c0 < end; c0 += 64) {
        const int jl = c0 + lane;
        const bool valid = jl < end;
        const int2 rec = srcea[valid ? jl : start];
        const int   srcl = rec.x;
        const float ea   = __int_as_float(rec.y);
        const float4 as = *(const float4*)&asrc[((size_t)b * N_ + srcl) * 4];
        float4 al;
        al.x = as.x + ad.x + ea * cc.x;
        al.y = as.y + ad.y + ea * cc.y;
        al.z = as.z + ad.z + ea * cc.z;
        al.w = as.w + ad.w + ea * cc.w;
        al.x = al.x > 0.f ? al.x : NEG_SLOPE * al.x;
        al.y = al.y > 0.f ? al.y : NEG_SLOPE * al.y;
        al.z = al.z > 0.f ? al.z : NEG_SLOPE * al.z;
        al.w = al.w > 0.f ? al.w : NEG_SLOPE * al.w;
        const float px = valid ? __expf(al.x) : 0.f;
        const float py = valid ? __expf(al.y) : 0.f;
        const float pz = valid ? __expf(al.z) : 0.f;
        const float pw = valid ? __expf(al.w) : 0.f;
        q0 += px; q1 += py; q2 += pz; q3 += pw;

        *(float4*)&pS[wave][lane][0] = make_float4(px, py, pz, pw);
        baseS[wave][lane] = (b * N_ + srcl) << 8;        // row base (ushorts)
        __builtin_amdgcn_wave_barrier();

        const int cnt = min(64, end - c0);
        const int lo4 = lane * 4;
        int j = 0;
        for (; j + 4 <= cnt; j += 4) {
            const float4 p0 = *(const float4*)&pS[wave][j + 0][0];
            const float4 p1 = *(const float4*)&pS[wave][j + 1][0];
            const float4 p2 = *(const float4*)&pS[wave][j + 2][0];
            const float4 p3 = *(const float4*)&pS[wave][j + 3][0];
            const int r0 = baseS[wave][j + 0];
            const int r1 = baseS[wave][j + 1];
            const int r2 = baseS[wave][j + 2];
            const int r3 = baseS[wave][j + 3];
            const ushort4 h0 = *(const ushort4*)&hbu[(size_t)r0 + lo4];
            const ushort4 h1 = *(const ushort4*)&hbu[(size_t)r1 + lo4];
            const ushort4 h2 = *(const ushort4*)&hbu[(size_t)r2 + lo4];
            const ushort4 h3 = *(const ushort4*)&hbu[(size_t)r3 + lo4];
            a0[0] = fmaf(p0.x, bf2f(h0.x), a0[0]);
            a0[1] = fmaf(p0.y, bf2f(h0.y), a0[1]);
            a0[2] = fmaf(p0.z, bf2f(h0.z), a0[2]);
            a0[3] = fmaf(p0.w, bf2f(h0.w), a0[3]);
            a1[0] = fmaf(p1.x, bf2f(h1.x), a1[0]);
            a1[1] = fmaf(p1.y, bf2f(h1.y), a1[1]);
            a1[2] = fmaf(p1.z, bf2f(h1.z), a1[2]);
            a1[3] = fmaf(p1.w, bf2f(h1.w), a1[3]);
            a2[0] = fmaf(p2.x, bf2f(h2.x), a2[0]);
            a2[1] = fmaf(p2.y, bf2f(h2.y), a2[1]);
            a2[2] = fmaf(p2.z, bf2f(h2.z), a2[2]);
            a2[3] = fmaf(p2.w, bf2f(h2.w), a2[3]);
            a3[0] = fmaf(p3.x, bf2f(h3.x), a3[0]);
            a3[1] = fmaf(p3.y, bf2f(h3.y), a3[1]);
            a3[2] = fmaf(p3.z, bf2f(h3.z), a3[2]);
            a3[3] = fmaf(p3.w, bf2f(h3.w), a3[3]);
        }
        for (; j < cnt; ++j) {
            const float4 p0 = *(const float4*)&pS[wave][j][0];
            const int    r0 = baseS[wave][j];
            const ushort4 h0 = *(const ushort4*)&hbu[(size_t)r0 + lo4];
            a0[0] = fmaf(p0.x, bf2f(h0.x), a0[0]);
            a0[1] = fmaf(p0.y, bf2f(h0.y), a0[1]);
            a0[2] = fmaf(p0.z, bf2f(h0.z), a0[2]);
            a0[3] = fmaf(p0.w, bf2f(h0.w), a0[3]);
        }
        __builtin_amdgcn_wave_barrier();
    }

    // denominator: butterfly reduce-all over lanes
#pragma unroll
    for (int off = 32; off > 0; off >>= 1) {
        q0 += __shfl_xor(q0, off, 64);
        q1 += __shfl_xor(q1, off, 64);
        q2 += __shfl_xor(q2, off, 64);
        q3 += __shfl_xor(q3, off, 64);
    }

    const float r = (a0[0] + a1[0] + a2[0] + a3[0]) / fmaxf(q0, 1e-16f)
                  + (a0[1] + a1[1] + a2[1] + a3[1]) / fmaxf(q1, 1e-16f)
                  + (a0[2] + a1[2] + a2[2] + a3[2]) / fmaxf(q2, 1e-16f)
                  + (a0[3] + a1[3] + a2[3] + a3[3]) / fmaxf(q3, 1e-16f);
    out[((size_t)b * N_ + dst) * O_ + lane] = 0.25f * r + bias[lane];
}

// ---------------------------------------------------------------------------
extern "C" void kernel_launch(void* const* d_in, const int* in_sizes, int n_in,
                              void* d_out, int out_size, void* d_ws, size_t ws_size,
                              hipStream_t stream)
{
    (void)in_sizes; (void)n_in; (void)out_size; (void)ws_size;
    const float* x        = (const float*)d_in[0];
    const int*   ei       = (const int*)d_in[1];     // int64 in ref -> int32 here
    const float* eattr    = (const float*)d_in[2];
    const float* Wsrc     = (const float*)d_in[3];
    const float* att_src  = (const float*)d_in[4];
    const float* att_dst  = (const float*)d_in[5];
    const float* W_edge   = (const float*)d_in[6];
    const float* att_edge = (const float*)d_in[7];
    const float* bias     = (const float*)d_in[8];
    float* out = (float*)d_out;

    // workspace carve-up (16B-aligned chunks)
    char* w = (char*)d_ws;
    auto take = [&](size_t bytes) { char* p = w; w += (bytes + 15) & ~size_t(15); return p; };
    unsigned short* hb   = (unsigned short*)take((size_t)B_ * N_ * O_ * H_ * 2); // 20.48 MB
    float* asrc    = (float*)take((size_t)B_ * N_ * H_ * 4);                     // 640 KB
    float* adst    = (float*)take((size_t)B_ * N_ * H_ * 4);
    float* c       = (float*)take(4 * 4);
    unsigned short* W1t = (unsigned short*)take((size_t)256 * 128 * 2);          // 64 KB
    float* vsrc    = (float*)take((size_t)128 * 4 * 4);                          // 2 KB
    float* vdst    = (float*)take((size_t)128 * 4 * 4);
    int* deg       = (int*)take((size_t)N_ * 4);
    int* rowptr    = (int*)take((size_t)(N_ + 1) * 4);
    int* rank      = (int*)take((size_t)E_ * 4);                                 // 640 KB
    int2* srcea    = (int2*)take((size_t)E_ * 8);                                // 1.28 MB

    hipLaunchKernelGGL(k_prep, dim3(128), dim3(256), 0, stream,
                       Wsrc, att_src, att_dst, W_edge, att_edge,
                       W1t, vsrc, vdst, deg, c);
    hipLaunchKernelGGL(k_gemm, dim3((B_ * N_) / 32), dim3(256), 0, stream,
                       x, ei, W1t, vsrc, vdst, hb, asrc, adst, deg, rank);
    hipLaunchKernelGGL(k_scan, dim3(1), dim3(1024), 0, stream, deg, rowptr);
    hipLaunchKernelGGL(k_place, dim3((E_ + 255) / 256), dim3(256), 0, stream,
                       ei, eattr, rowptr, rank, srcea);
    hipLaunchKernelGGL(k_agg, dim3(N_ / 4 * B_), dim3(256), 0, stream,
                       rowptr, srcea, asrc, adst, c, hb, bias, out);
}